// Round 4
// baseline (155.915 us; speedup 1.0000x reference)
//
#include <hip/hip_runtime.h>

#define B 64
#define T 4096
#define AD 1024   // ATTN_RNN_DIM
#define HD 256    // HYPERNET_DIM
#define CH 32
#define KS 31
#define OD 128
#define PADW 15
#define CWN (CH*KS)   // 992
#define TILE_T 128
#define NTILE (T / TILE_T)   // 32

// ---------------- Kernel A: h[b,j] = tanh(dot(query[b,:], W1[j,:]) + b1[j])
__global__ __launch_bounds__(256) void k_hyper1(const float* __restrict__ q,
        const float* __restrict__ W1, const float* __restrict__ b1,
        float* __restrict__ h) {
    int wid  = blockIdx.x * 4 + (threadIdx.x >> 6);
    int lane = threadIdx.x & 63;
    int b = wid >> 8;
    int j = wid & 255;
    const float4* qr = (const float4*)(q  + (size_t)b * AD);
    const float4* wr = (const float4*)(W1 + (size_t)j * AD);
    float s = 0.f;
    #pragma unroll
    for (int m = 0; m < 4; ++m) {
        float4 a = qr[m * 64 + lane];
        float4 w = wr[m * 64 + lane];
        s += a.x * w.x + a.y * w.y + a.z * w.z + a.w * w.w;
    }
    #pragma unroll
    for (int off = 32; off > 0; off >>= 1)
        s += __shfl_down(s, off, 64);
    if (lane == 0) h[b * HD + j] = tanhf(s + b1[j]);
}

// ---------------- Kernel B: cw[b,r] = dot(h[b,:], W2[r,:]) + b2[r]
__global__ __launch_bounds__(256) void k_cw(const float* __restrict__ h,
        const float* __restrict__ W2, const float* __restrict__ b2,
        float* __restrict__ cw) {
    int b   = blockIdx.x >> 2;
    int qtr = blockIdx.x & 3;
    int tid = threadIdx.x;
    __shared__ float hs[HD];
    hs[tid] = h[(size_t)b * HD + tid];
    __syncthreads();
    int r = qtr * 248 + tid;
    if (tid < 248) {
        const float4* wr = (const float4*)(W2 + (size_t)r * HD);
        float s = 0.f;
        #pragma unroll
        for (int m = 0; m < HD / 4; ++m) {
            float4 w = wr[m];
            s += w.x * hs[4*m+0] + w.y * hs[4*m+1]
               + w.z * hs[4*m+2] + w.w * hs[4*m+3];
        }
        cw[(size_t)b * CWN + r] = s + b2[r];
    }
}

// ---------------- Kernel C: Gt[b, k*OD+o] = sum_c Wfc[o,c]*cw[b, c*KS+k]
__global__ __launch_bounds__(256) void k_G(const float* __restrict__ cw,
        const float* __restrict__ Wfc, float* __restrict__ Gt) {
    int b   = blockIdx.x >> 2;
    int qtr = blockIdx.x & 3;
    int tid = threadIdx.x;
    __shared__ float cws[CWN];
    __shared__ float wfs_t[CH * OD];   // [c][o]
    #pragma unroll
    for (int p = 0; p < 4; ++p) {
        int idx = p * 256 + tid;
        if (idx < CWN) cws[idx] = cw[(size_t)b * CWN + idx];
    }
    #pragma unroll
    for (int p = 0; p < 16; ++p) {
        int idx = p * 256 + tid;
        int o = idx >> 5, c = idx & 31;
        wfs_t[c * OD + o] = Wfc[idx];
    }
    __syncthreads();
    if (tid < 248) {
        int base = qtr * 992 + tid * 4;
        #pragma unroll
        for (int j = 0; j < 4; ++j) {
            int idx = base + j;
            int k = idx >> 7, o = idx & 127;
            float s = 0.f;
            #pragma unroll
            for (int c = 0; c < CH; ++c)
                s += wfs_t[c * OD + o] * cws[c * KS + k];
            Gt[(size_t)b * (KS * OD) + idx] = s;
        }
    }
}

// ---------------- Kernel D: out[b,t,o] = sum_k Gt[b,k,o]*pa[b,t+k-15] + bfc[o]
__device__ __forceinline__ void compute_chunk(const float* pa, int s0, float base,
                                              const float (&g)[KS], float (&acc)[8]) {
    float pw[40];
    const float4* lp = (const float4*)(pa + s0);   // s0 % 8 == 0 -> aligned
    #pragma unroll
    for (int q4 = 0; q4 < 10; ++q4) {
        float4 v = lp[q4];
        pw[q4*4+0] = v.x; pw[q4*4+1] = v.y; pw[q4*4+2] = v.z; pw[q4*4+3] = v.w;
    }
    #pragma unroll
    for (int tt = 0; tt < 8; ++tt) {
        float a = base;
        #pragma unroll
        for (int k = 0; k < KS; ++k)
            a += g[k] * pw[tt + k];
        acc[tt] = a;
    }
}

__device__ __forceinline__ void store_chunk(float* outb, int s0, const float (&acc)[8]) {
    // nontemporal: bypass L2 allocation so the 134MB write stream doesn't
    // thrash Gt/pa out of the XCD L2s
    #pragma unroll
    for (int tt = 0; tt < 8; ++tt)
        __builtin_nontemporal_store(acc[tt], outb + (size_t)(s0 + tt) * OD);
}

__global__ __launch_bounds__(256, 6) void k_conv(const float* __restrict__ pa_g,
        const float* __restrict__ Gt, const float* __restrict__ bfc,
        float* __restrict__ out) {
    // XCD-aware swizzle: grid 2048 = 8 XCDs x 256; keep a batch's tiles on one XCD
    int bid = blockIdx.x;
    int sid = (bid & 7) * 256 + (bid >> 3);
    int b    = sid >> 5;          // 32 tiles per b
    int tile = sid & 31;
    int t0   = tile * TILE_T;
    int tid  = threadIdx.x;
    __shared__ float Gl[KS * OD];        // 15.9 KB
    __shared__ float pa[TILE_T + 32];    // 160 floats

    #pragma unroll
    for (int p = 0; p < 16; ++p) {
        int idx = p * 256 + tid;
        if (idx < KS * OD) Gl[idx] = Gt[(size_t)b * (KS * OD) + idx];
    }
    if (tid < TILE_T + 32) {
        int g = t0 + tid - PADW;
        pa[tid] = (g >= 0 && g < T) ? pa_g[(size_t)b * T + g] : 0.f;
    }
    __syncthreads();

    int o = tid & 127, half = tid >> 7;
    float g[KS];
    #pragma unroll
    for (int k = 0; k < KS; ++k) g[k] = Gl[k * OD + o];
    float base = bfc[o];
    float* outb = out + ((size_t)b * T + t0) * OD + o;
    int h0 = half * 64;

    // natural-order ping-pong: store(c) is covered by compute(c+1)+store(c+1)
    // before acc buffer reuse at compute(c+2)
    float accA[8], accB[8];
    #pragma unroll
    for (int c = 0; c < 8; c += 2) {
        compute_chunk(pa, h0 + c * 8, base, g, accA);
        store_chunk(outb, h0 + c * 8, accA);
        compute_chunk(pa, h0 + (c + 1) * 8, base, g, accB);
        store_chunk(outb, h0 + (c + 1) * 8, accB);
    }
}

extern "C" void kernel_launch(void* const* d_in, const int* in_sizes, int n_in,
                              void* d_out, int out_size, void* d_ws, size_t ws_size,
                              hipStream_t stream) {
    const float* query = (const float*)d_in[0];
    const float* prev  = (const float*)d_in[1];
    const float* W1    = (const float*)d_in[2];
    const float* b1    = (const float*)d_in[3];
    const float* W2    = (const float*)d_in[4];
    const float* b2    = (const float*)d_in[5];
    const float* Wfc   = (const float*)d_in[6];
    const float* bfc   = (const float*)d_in[7];
    float* out = (float*)d_out;

    float* h  = (float*)d_ws;          // 16384 floats
    float* cw = h + B * HD;            // 63488 floats
    float* Gt = cw + B * CWN;          // 253952 floats

    k_hyper1<<<dim3(4096), dim3(256), 0, stream>>>(query, W1, b1, h);
    k_cw    <<<dim3(B * 4), dim3(256), 0, stream>>>(h, W2, b2, cw);
    k_G     <<<dim3(B * 4), dim3(256), 0, stream>>>(cw, Wfc, Gt);
    k_conv  <<<dim3(B * NTILE), dim3(256), 0, stream>>>(prev, Gt, bfc, out);
}

// Round 5
// 56.733 us; speedup vs baseline: 2.7482x; 2.7482x over previous
//
#include <hip/hip_runtime.h>

#define B 64
#define T 4096
#define AD 1024   // ATTN_RNN_DIM
#define HD 256    // HYPERNET_DIM
#define CH 32
#define KS 31
#define OD 128
#define PADW 15
#define CWN (CH*KS)   // 992
#define TILE_T 64
#define NTILE (T / TILE_T)   // 64
#define PADROW 132           // 128 + 4: keeps float4 alignment, spreads banks

// ---------------- Kernel A: h[b,j] = tanh(dot(query[b,:], W1[j,:]) + b1[j])
__global__ __launch_bounds__(256) void k_hyper1(const float* __restrict__ q,
        const float* __restrict__ W1, const float* __restrict__ b1,
        float* __restrict__ h) {
    int wid  = blockIdx.x * 4 + (threadIdx.x >> 6);
    int lane = threadIdx.x & 63;
    int b = wid >> 8;
    int j = wid & 255;
    const float4* qr = (const float4*)(q  + (size_t)b * AD);
    const float4* wr = (const float4*)(W1 + (size_t)j * AD);
    float s = 0.f;
    #pragma unroll
    for (int m = 0; m < 4; ++m) {
        float4 a = qr[m * 64 + lane];
        float4 w = wr[m * 64 + lane];
        s += a.x * w.x + a.y * w.y + a.z * w.z + a.w * w.w;
    }
    #pragma unroll
    for (int off = 32; off > 0; off >>= 1)
        s += __shfl_down(s, off, 64);
    if (lane == 0) h[b * HD + j] = tanhf(s + b1[j]);
}

// ---------------- Kernel B: cw[b,r] = dot(h[b,:], W2[r,:]) + b2[r]
__global__ __launch_bounds__(256) void k_cw(const float* __restrict__ h,
        const float* __restrict__ W2, const float* __restrict__ b2,
        float* __restrict__ cw) {
    int b   = blockIdx.x >> 2;
    int qtr = blockIdx.x & 3;
    int tid = threadIdx.x;
    __shared__ float hs[HD];
    hs[tid] = h[(size_t)b * HD + tid];
    __syncthreads();
    int r = qtr * 248 + tid;
    if (tid < 248) {
        const float4* wr = (const float4*)(W2 + (size_t)r * HD);
        float s = 0.f;
        #pragma unroll
        for (int m = 0; m < HD / 4; ++m) {
            float4 w = wr[m];
            s += w.x * hs[4*m+0] + w.y * hs[4*m+1]
               + w.z * hs[4*m+2] + w.w * hs[4*m+3];
        }
        cw[(size_t)b * CWN + r] = s + b2[r];
    }
}

// ---------------- Kernel C: Gt[b, k*OD+o] = sum_c Wfc[o,c]*cw[b, c*KS+k]
__global__ __launch_bounds__(256) void k_G(const float* __restrict__ cw,
        const float* __restrict__ Wfc, float* __restrict__ Gt) {
    int b   = blockIdx.x >> 2;
    int qtr = blockIdx.x & 3;
    int tid = threadIdx.x;
    __shared__ float cws[CWN];
    __shared__ float wfs_t[CH * OD];   // [c][o]
    #pragma unroll
    for (int p = 0; p < 4; ++p) {
        int idx = p * 256 + tid;
        if (idx < CWN) cws[idx] = cw[(size_t)b * CWN + idx];
    }
    #pragma unroll
    for (int p = 0; p < 16; ++p) {
        int idx = p * 256 + tid;
        int o = idx >> 5, c = idx & 31;
        wfs_t[c * OD + o] = Wfc[idx];
    }
    __syncthreads();
    if (tid < 248) {
        int base = qtr * 992 + tid * 4;
        #pragma unroll
        for (int j = 0; j < 4; ++j) {
            int idx = base + j;
            int k = idx >> 7, o = idx & 127;
            float s = 0.f;
            #pragma unroll
            for (int c = 0; c < CH; ++c)
                s += wfs_t[c * OD + o] * cws[c * KS + k];
            Gt[(size_t)b * (KS * OD) + idx] = s;
        }
    }
}

// ---------------- Kernel D: out[b,t,o] = sum_k Gt[b,k,o]*pa[b,t+k-15] + bfc[o]
// compute into LDS tile, then store as contiguous float4 (1KB/wave-instr)
__device__ __forceinline__ void compute_chunk(const float* pa, int s0, float base,
                                              const float (&g)[KS], float (&acc)[8]) {
    float pw[40];
    const float4* lp = (const float4*)(pa + s0);   // s0 % 8 == 0 -> aligned
    #pragma unroll
    for (int q4 = 0; q4 < 10; ++q4) {
        float4 v = lp[q4];
        pw[q4*4+0] = v.x; pw[q4*4+1] = v.y; pw[q4*4+2] = v.z; pw[q4*4+3] = v.w;
    }
    #pragma unroll
    for (int tt = 0; tt < 8; ++tt) {
        float a = base;
        #pragma unroll
        for (int k = 0; k < KS; ++k)
            a += g[k] * pw[tt + k];
        acc[tt] = a;
    }
}

__global__ __launch_bounds__(256, 4) void k_conv(const float* __restrict__ pa_g,
        const float* __restrict__ Gt, const float* __restrict__ bfc,
        float* __restrict__ out) {
    // XCD-aware swizzle: grid 4096 = 8 XCDs x 512; b's tiles stay on one XCD
    int bid = blockIdx.x;
    int sid = (bid & 7) * 512 + (bid >> 3);
    int b    = sid >> 6;          // 64 tiles per b
    int tile = sid & 63;
    int t0   = tile * TILE_T;
    int tid  = threadIdx.x;
    __shared__ float tileo[TILE_T][PADROW];   // 33.8 KB
    __shared__ float pa[TILE_T + 32];         // 96 floats

    if (tid < TILE_T + 32) {
        int g = t0 + tid - PADW;
        pa[tid] = (g >= 0 && g < T) ? pa_g[(size_t)b * T + g] : 0.f;
    }
    int o = tid & 127, half = tid >> 7;
    float g[KS];
    #pragma unroll
    for (int k = 0; k < KS; ++k)
        g[k] = Gt[(size_t)b * (KS * OD) + k * OD + o];   // coalesced, L2-hot
    float base = bfc[o];
    __syncthreads();

    #pragma unroll
    for (int c = 0; c < 4; ++c) {            // 4 chunks of 8 t's per half
        int s0 = half * 32 + c * 8;
        float acc[8];
        compute_chunk(pa, s0, base, g, acc);
        #pragma unroll
        for (int tt = 0; tt < 8; ++tt)
            tileo[s0 + tt][o] = acc[tt];     // 2-way bank alias: free
    }
    __syncthreads();

    // cooperative vectorized store: 8 iters x (256 thr x 16B) = 64 KB tile
    size_t obase = ((size_t)b * T + t0) * OD;
    #pragma unroll
    for (int it = 0; it < 8; ++it) {
        int flat = it * 1024 + tid * 4;      // tile-flat index == global-flat
        int t = flat >> 7, oo = flat & 127;
        float4 v = *(const float4*)&tileo[t][oo];
        *(float4*)(out + obase + flat) = v;  // 1KB contiguous per wave
    }
}

extern "C" void kernel_launch(void* const* d_in, const int* in_sizes, int n_in,
                              void* d_out, int out_size, void* d_ws, size_t ws_size,
                              hipStream_t stream) {
    const float* query = (const float*)d_in[0];
    const float* prev  = (const float*)d_in[1];
    const float* W1    = (const float*)d_in[2];
    const float* b1    = (const float*)d_in[3];
    const float* W2    = (const float*)d_in[4];
    const float* b2    = (const float*)d_in[5];
    const float* Wfc   = (const float*)d_in[6];
    const float* bfc   = (const float*)d_in[7];
    float* out = (float*)d_out;

    float* h  = (float*)d_ws;          // 16384 floats
    float* cw = h + B * HD;            // 63488 floats
    float* Gt = cw + B * CWN;          // 253952 floats

    k_hyper1<<<dim3(4096), dim3(256), 0, stream>>>(query, W1, b1, h);
    k_cw    <<<dim3(B * 4), dim3(256), 0, stream>>>(h, W2, b2, cw);
    k_G     <<<dim3(B * 4), dim3(256), 0, stream>>>(cw, Wfc, Gt);
    k_conv  <<<dim3(B * NTILE), dim3(256), 0, stream>>>(prev, Gt, bfc, out);
}